// Round 1
// baseline (4169.400 us; speedup 1.0000x reference)
//
#include <hip/hip_runtime.h>
#include <math.h>

#define NN 50000
#define EE 1600000
#define DD 128
#define HH 4
#define CC 32
#define NSTEP 3
#define NEG 0.2f

__device__ __forceinline__ void atomicMaxF(float* addr, float val) {
    // sign-aware monotonic int-punning: correct for mixed-sign floats
    if (val >= 0.0f) atomicMax((int*)addr, __float_as_int(val));
    else             atomicMin((unsigned int*)addr, __float_as_uint(val));
}

__device__ __forceinline__ float leaky(float v) {
    return v >= 0.0f ? v : NEG * v;
}

// h = x @ W   (N x 128) @ (128 x 128)
// block: 256 threads = 8 rows x 32 col-groups (4 cols each)
__global__ __launch_bounds__(256) void gemm_k(const float* __restrict__ X,
                                              const float* __restrict__ W,
                                              float* __restrict__ H) {
    __shared__ float xs[8 * DD];
    const int tid = threadIdx.x;
    const int row0 = blockIdx.x * 8;
    // stage 8 rows of x (1024 floats = 256 float4)
    ((float4*)xs)[tid] = ((const float4*)(X + (size_t)row0 * DD))[tid];
    __syncthreads();
    const int lane_c = tid & 31;   // col group: cols 4*lane_c..+3
    const int row_l  = tid >> 5;   // 0..7
    const float4* __restrict__ W4 = (const float4*)W;
    const float* __restrict__ xr = xs + row_l * DD;
    float4 acc = {0.f, 0.f, 0.f, 0.f};
    #pragma unroll 4
    for (int k = 0; k < DD; ++k) {
        const float xv = xr[k];
        const float4 wv = W4[k * 32 + lane_c];
        acc.x += xv * wv.x; acc.y += xv * wv.y;
        acc.z += xv * wv.z; acc.w += xv * wv.w;
    }
    ((float4*)(H + (size_t)(row0 + row_l) * DD))[lane_c] = acc;
}

// alpha_src/alpha_dst: per node, per head dot(h[n,h,:], a[h,:])
__global__ __launch_bounds__(256) void alpha_k(const float* __restrict__ H,
                                               const float* __restrict__ a_src,
                                               const float* __restrict__ a_dst,
                                               float* __restrict__ as_,
                                               float* __restrict__ ad_) {
    const int n = blockIdx.x * 256 + threadIdx.x;
    if (n >= NN) return;
    const float4* hp = (const float4*)(H + (size_t)n * DD);
    const float4* s4 = (const float4*)a_src;
    const float4* d4 = (const float4*)a_dst;
    #pragma unroll
    for (int h = 0; h < HH; ++h) {
        float ss = 0.f, dd = 0.f;
        #pragma unroll
        for (int i = 0; i < 8; ++i) {
            const float4 hv = hp[h * 8 + i];
            const float4 sv = s4[h * 8 + i];
            const float4 dv = d4[h * 8 + i];
            ss += hv.x * sv.x + hv.y * sv.y + hv.z * sv.z + hv.w * sv.w;
            dd += hv.x * dv.x + hv.y * dv.y + hv.z * dv.z + hv.w * dv.w;
        }
        as_[n * HH + h] = ss;
        ad_[n * HH + h] = dd;
    }
}

__global__ __launch_bounds__(256) void init_md(float* __restrict__ m,
                                               float* __restrict__ denom) {
    const int i = blockIdx.x * 256 + threadIdx.x;
    if (i < NN * HH) { m[i] = -INFINITY; denom[i] = 0.0f; }
}

// logits (leaky_relu) -> rel output slice + segment max over dst
__global__ __launch_bounds__(256) void logits_k(const int* __restrict__ ei,
                                                const float* __restrict__ as_,
                                                const float* __restrict__ ad_,
                                                float* __restrict__ rel,
                                                float* __restrict__ m) {
    const int e = blockIdx.x * 256 + threadIdx.x;
    if (e >= EE) return;
    const int s = ei[e], d = ei[EE + e];
    const float4 av = *(const float4*)(as_ + (size_t)s * HH);
    const float4 bv = *(const float4*)(ad_ + (size_t)d * HH);
    float4 l;
    l.x = leaky(av.x + bv.x); l.y = leaky(av.y + bv.y);
    l.z = leaky(av.z + bv.z); l.w = leaky(av.w + bv.w);
    *(float4*)(rel + (size_t)e * HH) = l;
    float* mp = m + (size_t)d * HH;
    atomicMaxF(mp + 0, l.x); atomicMaxF(mp + 1, l.y);
    atomicMaxF(mp + 2, l.z); atomicMaxF(mp + 3, l.w);
}

__global__ __launch_bounds__(256) void finm_k(float* __restrict__ m) {
    const int i = blockIdx.x * 256 + threadIdx.x;
    if (i < NN * HH) {
        const float v = m[i];
        if (!isfinite(v)) m[i] = 0.0f;
    }
}

// denom = segment_sum(exp(logit - m[dst]))
__global__ __launch_bounds__(256) void expsum_k(const int* __restrict__ ei,
                                                const float* __restrict__ rel,
                                                const float* __restrict__ m,
                                                float* __restrict__ denom) {
    const int e = blockIdx.x * 256 + threadIdx.x;
    if (e >= EE) return;
    const int d = ei[EE + e];
    const float4 l = *(const float4*)(rel + (size_t)e * HH);
    const float4 mv = *(const float4*)(m + (size_t)d * HH);
    float* dp = denom + (size_t)d * HH;
    atomicAdd(dp + 0, expf(l.x - mv.x));
    atomicAdd(dp + 1, expf(l.y - mv.y));
    atomicAdd(dp + 2, expf(l.z - mv.z));
    atomicAdd(dp + 3, expf(l.w - mv.w));
}

// attn = exp(logit - m[dst]) / (denom[dst] + 1e-16)
__global__ __launch_bounds__(256) void attn_k(const int* __restrict__ ei,
                                              const float* __restrict__ rel,
                                              const float* __restrict__ m,
                                              const float* __restrict__ denom,
                                              float* __restrict__ attn) {
    const int e = blockIdx.x * 256 + threadIdx.x;
    if (e >= EE) return;
    const int d = ei[EE + e];
    const float4 l = *(const float4*)(rel + (size_t)e * HH);
    const float4 mv = *(const float4*)(m + (size_t)d * HH);
    const float4 dv = *(const float4*)(denom + (size_t)d * HH);
    float4 a;
    a.x = expf(l.x - mv.x) / (dv.x + 1e-16f);
    a.y = expf(l.y - mv.y) / (dv.y + 1e-16f);
    a.z = expf(l.z - mv.z) / (dv.z + 1e-16f);
    a.w = expf(l.w - mv.w) / (dv.w + 1e-16f);
    *(float4*)(attn + (size_t)e * HH) = a;
}

// xnew = xprev  (float4 copy)
__global__ __launch_bounds__(256) void copy_k(const float* __restrict__ src,
                                              float* __restrict__ dst) {
    const int i = blockIdx.x * 256 + threadIdx.x;
    ((float4*)dst)[i] = ((const float4*)src)[i];
}

// xnew[dst] += h[src] * attn   (2 edges per 256-thread block, 128 threads/edge)
__global__ __launch_bounds__(256) void msg_k(const int* __restrict__ ei,
                                             const float* __restrict__ attn,
                                             const float* __restrict__ H,
                                             float* __restrict__ xnew) {
    const int tid = threadIdx.x;
    const int e = blockIdx.x * 2 + (tid >> 7);
    const int t = tid & 127;
    const int s = ei[e], d = ei[EE + e];
    const float a = attn[(size_t)e * HH + (t >> 5)];
    const float v = H[(size_t)s * DD + t] * a;
    atomicAdd(&xnew[(size_t)d * DD + t], v);
}

extern "C" void kernel_launch(void* const* d_in, const int* in_sizes, int n_in,
                              void* d_out, int out_size, void* d_ws, size_t ws_size,
                              hipStream_t stream) {
    const float* x     = (const float*)d_in[0];
    const int*   ei    = (const int*)d_in[1];
    const float* W     = (const float*)d_in[2];
    const float* a_src = (const float*)d_in[3];
    const float* a_dst = (const float*)d_in[4];

    float* xs_out   = (float*)d_out;                         // [3,N,128]
    float* attn_out = xs_out + (size_t)NSTEP * NN * DD;      // [3,E,4]
    float* rel_out  = attn_out + (size_t)NSTEP * EE * HH;    // [3,E,4]

    float* h     = (float*)d_ws;                 // N*128
    float* as_   = h + (size_t)NN * DD;          // N*4
    float* ad_   = as_ + (size_t)NN * HH;        // N*4
    float* m     = ad_ + (size_t)NN * HH;        // N*4
    float* denom = m + (size_t)NN * HH;          // N*4

    const float* xprev = x;
    for (int s = 0; s < NSTEP; ++s) {
        float* xs_s = xs_out + (size_t)s * NN * DD;
        float* at_s = attn_out + (size_t)s * EE * HH;
        float* rl_s = rel_out + (size_t)s * EE * HH;

        gemm_k<<<NN / 8, 256, 0, stream>>>(xprev, W, h);
        alpha_k<<<(NN + 255) / 256, 256, 0, stream>>>(h, a_src, a_dst, as_, ad_);
        init_md<<<(NN * HH + 255) / 256, 256, 0, stream>>>(m, denom);
        logits_k<<<EE / 256, 256, 0, stream>>>(ei, as_, ad_, rl_s, m);
        finm_k<<<(NN * HH + 255) / 256, 256, 0, stream>>>(m);
        expsum_k<<<EE / 256, 256, 0, stream>>>(ei, rl_s, m, denom);
        attn_k<<<EE / 256, 256, 0, stream>>>(ei, rl_s, m, denom, at_s);
        copy_k<<<NN * DD / 4 / 256, 256, 0, stream>>>(xprev, xs_s);
        msg_k<<<EE / 2, 256, 0, stream>>>(ei, at_s, h, xs_s);

        xprev = xs_s;
    }
}

// Round 3
// 1249.681 us; speedup vs baseline: 3.3364x; 3.3364x over previous
//
#include <hip/hip_runtime.h>
#include <math.h>

#define NN 50000
#define EE 1600000
#define DD 128
#define HH 4
#define NSTEP 3
#define NEG 0.2f
#define CAP 256   // LDS stash capacity per node (avg degree 32; spill path handles larger)

__device__ __forceinline__ float leaky(float v) { return v >= 0.0f ? v : NEG * v; }

// ---------------- h = x @ W  (N x 128) @ (128 x 128) ----------------
__global__ __launch_bounds__(256) void gemm_k(const float* __restrict__ X,
                                              const float* __restrict__ W,
                                              float* __restrict__ H) {
    __shared__ float xs[8 * DD];
    const int tid = threadIdx.x;
    const int row0 = blockIdx.x * 8;
    ((float4*)xs)[tid] = ((const float4*)(X + (size_t)row0 * DD))[tid];
    __syncthreads();
    const int lane_c = tid & 31;
    const int row_l  = tid >> 5;
    const float4* __restrict__ W4 = (const float4*)W;
    const float* __restrict__ xr = xs + row_l * DD;
    float4 acc = {0.f, 0.f, 0.f, 0.f};
    #pragma unroll 4
    for (int k = 0; k < DD; ++k) {
        const float xv = xr[k];
        const float4 wv = W4[k * 32 + lane_c];
        acc.x += xv * wv.x; acc.y += xv * wv.y;
        acc.z += xv * wv.z; acc.w += xv * wv.w;
    }
    ((float4*)(H + (size_t)(row0 + row_l) * DD))[lane_c] = acc;
}

// ---------------- per-node head dots ----------------
__global__ __launch_bounds__(256) void alpha_k(const float* __restrict__ H,
                                               const float* __restrict__ a_src,
                                               const float* __restrict__ a_dst,
                                               float* __restrict__ as_,
                                               float* __restrict__ ad_) {
    const int n = blockIdx.x * 256 + threadIdx.x;
    if (n >= NN) return;
    const float4* hp = (const float4*)(H + (size_t)n * DD);
    const float4* s4 = (const float4*)a_src;
    const float4* d4 = (const float4*)a_dst;
    #pragma unroll
    for (int h = 0; h < HH; ++h) {
        float ss = 0.f, dd = 0.f;
        #pragma unroll
        for (int i = 0; i < 8; ++i) {
            const float4 hv = hp[h * 8 + i];
            const float4 sv = s4[h * 8 + i];
            const float4 dv = d4[h * 8 + i];
            ss += hv.x * sv.x + hv.y * sv.y + hv.z * sv.z + hv.w * sv.w;
            dd += hv.x * dv.x + hv.y * dv.y + hv.z * dv.z + hv.w * dv.w;
        }
        as_[n * HH + h] = ss;
        ad_[n * HH + h] = dd;
    }
}

// ---------------- CSR build ----------------
__global__ __launch_bounds__(256) void zero_k(int* __restrict__ p, int n) {
    const int i = blockIdx.x * 256 + threadIdx.x;
    if (i < n) p[i] = 0;
}

__global__ __launch_bounds__(256) void deg_k(const int* __restrict__ ei, int* __restrict__ deg) {
    const int e = blockIdx.x * 256 + threadIdx.x;
    if (e < EE) atomicAdd(&deg[ei[EE + e]], 1);
}

// exclusive scan deg[N] -> row_ptr[N+1]; zero cursor
__global__ __launch_bounds__(1024) void scan_k(const int* __restrict__ deg,
                                               int* __restrict__ row_ptr,
                                               int* __restrict__ cursor) {
    __shared__ int part[1024];
    const int tid = threadIdx.x;
    const int per = (NN + 1023) / 1024;
    const int base = tid * per;
    int sum = 0;
    for (int i = 0; i < per; ++i) {
        const int idx = base + i;
        if (idx < NN) sum += deg[idx];
    }
    part[tid] = sum;
    __syncthreads();
    for (int off = 1; off < 1024; off <<= 1) {
        const int v = part[tid];
        const int add = (tid >= off) ? part[tid - off] : 0;
        __syncthreads();
        part[tid] = v + add;
        __syncthreads();
    }
    int run = (tid == 0) ? 0 : part[tid - 1];
    for (int i = 0; i < per; ++i) {
        const int idx = base + i;
        if (idx < NN) {
            row_ptr[idx] = run;
            run += deg[idx];
            cursor[idx] = 0;
        }
    }
    if (tid == 1023) row_ptr[NN] = run;
}

__global__ __launch_bounds__(256) void scat_k(const int* __restrict__ ei,
                                              const int* __restrict__ row_ptr,
                                              int* __restrict__ cursor,
                                              int* __restrict__ csr_src,
                                              int* __restrict__ csr_eid) {
    const int e = blockIdx.x * 256 + threadIdx.x;
    if (e >= EE) return;
    const int s = ei[e], d = ei[EE + e];
    const int pos = row_ptr[d] + atomicAdd(&cursor[d], 1);
    csr_src[pos] = s;
    csr_eid[pos] = e;
}

// ---------------- fused per-destination edge phase ----------------
// one block (128 threads) per node: logits -> rel, seg-max, exp -> denom,
// attn write, msg aggregation (reg accumulator, channel = tid), residual.
__global__ __launch_bounds__(128) void node_k(const int* __restrict__ row_ptr,
                                              const int* __restrict__ csr_src,
                                              const int* __restrict__ csr_eid,
                                              const float* __restrict__ as_,
                                              const float* __restrict__ ad_,
                                              const float* __restrict__ H,
                                              const float* __restrict__ xprev,
                                              float* __restrict__ rel,
                                              float* __restrict__ attn,
                                              float* __restrict__ xout) {
    __shared__ int    src_l[CAP];
    __shared__ int    eid_l[CAP];
    __shared__ float4 exp_l[CAP];
    __shared__ float4 redbuf[2];

    const int n = blockIdx.x;
    const int tid = threadIdx.x;
    const int row0 = row_ptr[n];
    const int deg = row_ptr[n + 1] - row0;

    if (deg == 0) {
        xout[(size_t)n * DD + tid] = xprev[(size_t)n * DD + tid];
        return;
    }

    const float4 adv = *(const float4*)(ad_ + (size_t)n * HH);

    // Phase A: logits -> rel, stash, per-thread max
    float4 mx = {-INFINITY, -INFINITY, -INFINITY, -INFINITY};
    for (int j = tid; j < deg; j += 128) {
        const int s = csr_src[row0 + j];
        const int e = csr_eid[row0 + j];
        const float4 av = *(const float4*)(as_ + (size_t)s * HH);
        float4 l;
        l.x = leaky(av.x + adv.x); l.y = leaky(av.y + adv.y);
        l.z = leaky(av.z + adv.z); l.w = leaky(av.w + adv.w);
        *(float4*)(rel + (size_t)e * HH) = l;
        if (j < CAP) { src_l[j] = s; eid_l[j] = e; exp_l[j] = l; }
        mx.x = fmaxf(mx.x, l.x); mx.y = fmaxf(mx.y, l.y);
        mx.z = fmaxf(mx.z, l.z); mx.w = fmaxf(mx.w, l.w);
    }
    // block max reduce (wave shfl, then combine 2 waves)
    #pragma unroll
    for (int off = 1; off < 64; off <<= 1) {
        mx.x = fmaxf(mx.x, __shfl_xor(mx.x, off));
        mx.y = fmaxf(mx.y, __shfl_xor(mx.y, off));
        mx.z = fmaxf(mx.z, __shfl_xor(mx.z, off));
        mx.w = fmaxf(mx.w, __shfl_xor(mx.w, off));
    }
    if ((tid & 63) == 0) redbuf[tid >> 6] = mx;
    __syncthreads();
    {
        const float4 a = redbuf[0], b = redbuf[1];
        mx.x = fmaxf(a.x, b.x); mx.y = fmaxf(a.y, b.y);
        mx.z = fmaxf(a.z, b.z); mx.w = fmaxf(a.w, b.w);
    }
    __syncthreads();

    // Phase B: exp, denom
    float4 ds = {0.f, 0.f, 0.f, 0.f};
    for (int j = tid; j < deg; j += 128) {
        float4 l;
        if (j < CAP) l = exp_l[j];
        else {
            const int s = csr_src[row0 + j];
            const float4 av = *(const float4*)(as_ + (size_t)s * HH);
            l.x = leaky(av.x + adv.x); l.y = leaky(av.y + adv.y);
            l.z = leaky(av.z + adv.z); l.w = leaky(av.w + adv.w);
        }
        float4 e4;
        e4.x = expf(l.x - mx.x); e4.y = expf(l.y - mx.y);
        e4.z = expf(l.z - mx.z); e4.w = expf(l.w - mx.w);
        if (j < CAP) exp_l[j] = e4;
        ds.x += e4.x; ds.y += e4.y; ds.z += e4.z; ds.w += e4.w;
    }
    #pragma unroll
    for (int off = 1; off < 64; off <<= 1) {
        ds.x += __shfl_xor(ds.x, off); ds.y += __shfl_xor(ds.y, off);
        ds.z += __shfl_xor(ds.z, off); ds.w += __shfl_xor(ds.w, off);
    }
    if ((tid & 63) == 0) redbuf[tid >> 6] = ds;
    __syncthreads();
    {
        const float4 a = redbuf[0], b = redbuf[1];
        ds.x = a.x + b.x; ds.y = a.y + b.y; ds.z = a.z + b.z; ds.w = a.w + b.w;
    }
    float4 inv;
    inv.x = 1.0f / (ds.x + 1e-16f); inv.y = 1.0f / (ds.y + 1e-16f);
    inv.z = 1.0f / (ds.z + 1e-16f); inv.w = 1.0f / (ds.w + 1e-16f);

    // Phase B2: attn write
    for (int j = tid; j < deg; j += 128) {
        float4 e4; int e;
        if (j < CAP) { e4 = exp_l[j]; e = eid_l[j]; }
        else {
            const int s = csr_src[row0 + j];
            e = csr_eid[row0 + j];
            const float4 av = *(const float4*)(as_ + (size_t)s * HH);
            float4 l;
            l.x = leaky(av.x + adv.x); l.y = leaky(av.y + adv.y);
            l.z = leaky(av.z + adv.z); l.w = leaky(av.w + adv.w);
            e4.x = expf(l.x - mx.x); e4.y = expf(l.y - mx.y);
            e4.z = expf(l.z - mx.z); e4.w = expf(l.w - mx.w);
        }
        float4 a;
        a.x = e4.x * inv.x; a.y = e4.y * inv.y;
        a.z = e4.z * inv.z; a.w = e4.w * inv.w;
        *(float4*)(attn + (size_t)e * HH) = a;
    }
    __syncthreads();

    // Phase C: message aggregation; channel c = tid, head = tid>>5
    const int hsel = tid >> 5;
    const float invh = (hsel == 0) ? inv.x : (hsel == 1) ? inv.y : (hsel == 2) ? inv.z : inv.w;
    float acc = 0.f;
    const int dcap = deg < CAP ? deg : CAP;
    const float* el = (const float*)exp_l;
    #pragma unroll 4
    for (int j = 0; j < dcap; ++j) {
        const int s = __builtin_amdgcn_readfirstlane(src_l[j]);
        const float a = el[j * 4 + hsel] * invh;
        acc += H[(size_t)s * DD + tid] * a;
    }
    for (int j = dcap; j < deg; ++j) {   // spill path (deg > CAP), reads attn we wrote
        const int s = csr_src[row0 + j];
        const int e = csr_eid[row0 + j];
        const float a = attn[(size_t)e * HH + hsel];
        acc += H[(size_t)s * DD + tid] * a;
    }
    xout[(size_t)n * DD + tid] = xprev[(size_t)n * DD + tid] + acc;
}

extern "C" void kernel_launch(void* const* d_in, const int* in_sizes, int n_in,
                              void* d_out, int out_size, void* d_ws, size_t ws_size,
                              hipStream_t stream) {
    const float* x     = (const float*)d_in[0];
    const int*   ei    = (const int*)d_in[1];
    const float* W     = (const float*)d_in[2];
    const float* a_src = (const float*)d_in[3];
    const float* a_dst = (const float*)d_in[4];

    float* xs_out   = (float*)d_out;                         // [3,N,128]
    float* attn_out = xs_out + (size_t)NSTEP * NN * DD;      // [3,E,4]
    float* rel_out  = attn_out + (size_t)NSTEP * EE * HH;    // [3,E,4]

    float* h      = (float*)d_ws;                  // N*128
    float* as_    = h + (size_t)NN * DD;           // N*4
    float* ad_    = as_ + (size_t)NN * HH;         // N*4
    int*   deg    = (int*)(ad_ + (size_t)NN * HH); // N
    int*   cursor = deg + NN;                      // N
    int*   rowp   = cursor + NN;                   // N+1 (pad to 8)
    int*   csr_s  = rowp + NN + 8;                 // E
    int*   csr_e  = csr_s + EE;                    // E

    // CSR build (edge_index is constant across steps)
    zero_k<<<(NN + 255) / 256, 256, 0, stream>>>(deg, NN);
    deg_k<<<(EE + 255) / 256, 256, 0, stream>>>(ei, deg);
    scan_k<<<1, 1024, 0, stream>>>(deg, rowp, cursor);
    scat_k<<<(EE + 255) / 256, 256, 0, stream>>>(ei, rowp, cursor, csr_s, csr_e);

    const float* xprev = x;
    for (int s = 0; s < NSTEP; ++s) {
        float* xs_s = xs_out + (size_t)s * NN * DD;
        float* at_s = attn_out + (size_t)s * EE * HH;
        float* rl_s = rel_out + (size_t)s * EE * HH;

        gemm_k<<<NN / 8, 256, 0, stream>>>(xprev, W, h);
        alpha_k<<<(NN + 255) / 256, 256, 0, stream>>>(h, a_src, a_dst, as_, ad_);
        node_k<<<NN, 128, 0, stream>>>(rowp, csr_s, csr_e, as_, ad_, h, xprev,
                                       rl_s, at_s, xs_s);
        xprev = xs_s;
    }
}

// Round 4
// 1141.500 us; speedup vs baseline: 3.6526x; 1.0948x over previous
//
#include <hip/hip_runtime.h>
#include <math.h>

#define NN 50000
#define EE 1600000
#define DD 128
#define HH 4
#define NSTEP 3
#define NEG 0.2f
#define CAP 256   // LDS stash capacity per node (avg degree 32; spill path handles larger)
#define GA_ROWS 8
#define GA_BLOCKS 512

__device__ __forceinline__ float leaky(float v) { return v >= 0.0f ? v : NEG * v; }

// ---------------- fused h = x@W and alpha dots ----------------
// W staged in LDS once per block; grid-stride over 8-row tiles.
// thread (row_l=tid>>5, lane_c=tid&31) owns cols {lane_c+32*i}, i=0..3 == head i.
__global__ __launch_bounds__(256) void gemm_alpha_k(const float* __restrict__ X,
                                                    const float* __restrict__ W,
                                                    const float* __restrict__ a_src,
                                                    const float* __restrict__ a_dst,
                                                    float* __restrict__ H,
                                                    float* __restrict__ as_,
                                                    float* __restrict__ ad_) {
    __shared__ float wsh[DD * DD];       // 64 KB
    __shared__ float xs[GA_ROWS * DD];   // 4 KB
    const int tid = threadIdx.x;
    {   // stage W (16384 floats = 4096 float4, 16 per thread)
        const float4* Wg = (const float4*)W;
        float4* Wl = (float4*)wsh;
        #pragma unroll
        for (int i = 0; i < 16; ++i) Wl[tid + 256 * i] = Wg[tid + 256 * i];
    }
    const int lane_c = tid & 31;
    const int row_l  = tid >> 5;
    float asv[HH], adv[HH];
    #pragma unroll
    for (int h = 0; h < HH; ++h) {
        asv[h] = a_src[h * 32 + lane_c];
        adv[h] = a_dst[h * 32 + lane_c];
    }
    __syncthreads();

    for (int row0 = blockIdx.x * GA_ROWS; row0 < NN; row0 += GA_BLOCKS * GA_ROWS) {
        ((float4*)xs)[tid] = ((const float4*)(X + (size_t)row0 * DD))[tid];
        __syncthreads();
        float acc0 = 0.f, acc1 = 0.f, acc2 = 0.f, acc3 = 0.f;
        const float* xr = xs + row_l * DD;
        #pragma unroll 4
        for (int k = 0; k < DD; ++k) {
            const float xv = xr[k];
            const float* wr = wsh + k * DD + lane_c;
            acc0 += xv * wr[0];
            acc1 += xv * wr[32];
            acc2 += xv * wr[64];
            acc3 += xv * wr[96];
        }
        const int n = row0 + row_l;
        float* Hr = H + (size_t)n * DD;
        Hr[lane_c] = acc0; Hr[lane_c + 32] = acc1;
        Hr[lane_c + 64] = acc2; Hr[lane_c + 96] = acc3;
        // fused alpha: per head h, reduce acc_h * a[h][lane_c] over 32 lanes
        float ps0 = acc0 * asv[0], ps1 = acc1 * asv[1], ps2 = acc2 * asv[2], ps3 = acc3 * asv[3];
        float pd0 = acc0 * adv[0], pd1 = acc1 * adv[1], pd2 = acc2 * adv[2], pd3 = acc3 * adv[3];
        #pragma unroll
        for (int off = 1; off < 32; off <<= 1) {
            ps0 += __shfl_xor(ps0, off); ps1 += __shfl_xor(ps1, off);
            ps2 += __shfl_xor(ps2, off); ps3 += __shfl_xor(ps3, off);
            pd0 += __shfl_xor(pd0, off); pd1 += __shfl_xor(pd1, off);
            pd2 += __shfl_xor(pd2, off); pd3 += __shfl_xor(pd3, off);
        }
        if (lane_c == 0) {
            float* asp = as_ + (size_t)n * HH;
            float* adp = ad_ + (size_t)n * HH;
            asp[0] = ps0; asp[1] = ps1; asp[2] = ps2; asp[3] = ps3;
            adp[0] = pd0; adp[1] = pd1; adp[2] = pd2; adp[3] = pd3;
        }
        __syncthreads();
    }
}

// ---------------- CSR build ----------------
__global__ __launch_bounds__(256) void zero_k(int* __restrict__ p, int n) {
    const int i = blockIdx.x * 256 + threadIdx.x;
    if (i < n) p[i] = 0;
}

__global__ __launch_bounds__(256) void deg_k(const int* __restrict__ ei, int* __restrict__ deg) {
    const int e = blockIdx.x * 256 + threadIdx.x;
    if (e < EE) atomicAdd(&deg[ei[EE + e]], 1);
}

// exclusive scan deg[N] -> row_ptr[N+1]; zero cursor
__global__ __launch_bounds__(1024) void scan_k(const int* __restrict__ deg,
                                               int* __restrict__ row_ptr,
                                               int* __restrict__ cursor) {
    __shared__ int part[1024];
    const int tid = threadIdx.x;
    const int per = (NN + 1023) / 1024;
    const int base = tid * per;
    int sum = 0;
    for (int i = 0; i < per; ++i) {
        const int idx = base + i;
        if (idx < NN) sum += deg[idx];
    }
    part[tid] = sum;
    __syncthreads();
    for (int off = 1; off < 1024; off <<= 1) {
        const int v = part[tid];
        const int add = (tid >= off) ? part[tid - off] : 0;
        __syncthreads();
        part[tid] = v + add;
        __syncthreads();
    }
    int run = (tid == 0) ? 0 : part[tid - 1];
    for (int i = 0; i < per; ++i) {
        const int idx = base + i;
        if (idx < NN) {
            row_ptr[idx] = run;
            run += deg[idx];
            cursor[idx] = 0;
        }
    }
    if (tid == 1023) row_ptr[NN] = run;
}

__global__ __launch_bounds__(256) void scat_k(const int* __restrict__ ei,
                                              const int* __restrict__ row_ptr,
                                              int* __restrict__ cursor,
                                              int* __restrict__ csr_src,
                                              int* __restrict__ csr_eid) {
    const int e = blockIdx.x * 256 + threadIdx.x;
    if (e >= EE) return;
    const int s = ei[e], d = ei[EE + e];
    const int pos = row_ptr[d] + atomicAdd(&cursor[d], 1);
    csr_src[pos] = s;
    csr_eid[pos] = e;
}

// ---------------- fused per-destination edge phase ----------------
__global__ __launch_bounds__(128) void node_k(const int* __restrict__ row_ptr,
                                              const int* __restrict__ csr_src,
                                              const int* __restrict__ csr_eid,
                                              const float* __restrict__ as_,
                                              const float* __restrict__ ad_,
                                              const float* __restrict__ H,
                                              const float* __restrict__ xprev,
                                              float* __restrict__ rel,
                                              float* __restrict__ attn,
                                              float* __restrict__ xout) {
    __shared__ int    src_l[CAP];
    __shared__ int    eid_l[CAP];
    __shared__ float4 exp_l[CAP];
    __shared__ float4 redbuf[2];

    const int n = blockIdx.x;
    const int tid = threadIdx.x;
    const int row0 = row_ptr[n];
    const int deg = row_ptr[n + 1] - row0;

    if (deg == 0) {
        xout[(size_t)n * DD + tid] = xprev[(size_t)n * DD + tid];
        return;
    }

    const float4 adv = *(const float4*)(ad_ + (size_t)n * HH);

    // Phase A: logits -> rel, stash, per-thread max
    float4 mx = {-INFINITY, -INFINITY, -INFINITY, -INFINITY};
    for (int j = tid; j < deg; j += 128) {
        const int s = csr_src[row0 + j];
        const int e = csr_eid[row0 + j];
        const float4 av = *(const float4*)(as_ + (size_t)s * HH);
        float4 l;
        l.x = leaky(av.x + adv.x); l.y = leaky(av.y + adv.y);
        l.z = leaky(av.z + adv.z); l.w = leaky(av.w + adv.w);
        *(float4*)(rel + (size_t)e * HH) = l;
        if (j < CAP) { src_l[j] = s; eid_l[j] = e; exp_l[j] = l; }
        mx.x = fmaxf(mx.x, l.x); mx.y = fmaxf(mx.y, l.y);
        mx.z = fmaxf(mx.z, l.z); mx.w = fmaxf(mx.w, l.w);
    }
    #pragma unroll
    for (int off = 1; off < 64; off <<= 1) {
        mx.x = fmaxf(mx.x, __shfl_xor(mx.x, off));
        mx.y = fmaxf(mx.y, __shfl_xor(mx.y, off));
        mx.z = fmaxf(mx.z, __shfl_xor(mx.z, off));
        mx.w = fmaxf(mx.w, __shfl_xor(mx.w, off));
    }
    if ((tid & 63) == 0) redbuf[tid >> 6] = mx;
    __syncthreads();
    {
        const float4 a = redbuf[0], b = redbuf[1];
        mx.x = fmaxf(a.x, b.x); mx.y = fmaxf(a.y, b.y);
        mx.z = fmaxf(a.z, b.z); mx.w = fmaxf(a.w, b.w);
    }
    __syncthreads();

    // Phase B: exp, denom
    float4 ds = {0.f, 0.f, 0.f, 0.f};
    for (int j = tid; j < deg; j += 128) {
        float4 l;
        if (j < CAP) l = exp_l[j];
        else {
            const int s = csr_src[row0 + j];
            const float4 av = *(const float4*)(as_ + (size_t)s * HH);
            l.x = leaky(av.x + adv.x); l.y = leaky(av.y + adv.y);
            l.z = leaky(av.z + adv.z); l.w = leaky(av.w + adv.w);
        }
        float4 e4;
        e4.x = expf(l.x - mx.x); e4.y = expf(l.y - mx.y);
        e4.z = expf(l.z - mx.z); e4.w = expf(l.w - mx.w);
        if (j < CAP) exp_l[j] = e4;
        ds.x += e4.x; ds.y += e4.y; ds.z += e4.z; ds.w += e4.w;
    }
    #pragma unroll
    for (int off = 1; off < 64; off <<= 1) {
        ds.x += __shfl_xor(ds.x, off); ds.y += __shfl_xor(ds.y, off);
        ds.z += __shfl_xor(ds.z, off); ds.w += __shfl_xor(ds.w, off);
    }
    if ((tid & 63) == 0) redbuf[tid >> 6] = ds;
    __syncthreads();
    {
        const float4 a = redbuf[0], b = redbuf[1];
        ds.x = a.x + b.x; ds.y = a.y + b.y; ds.z = a.z + b.z; ds.w = a.w + b.w;
    }
    float4 inv;
    inv.x = 1.0f / (ds.x + 1e-16f); inv.y = 1.0f / (ds.y + 1e-16f);
    inv.z = 1.0f / (ds.z + 1e-16f); inv.w = 1.0f / (ds.w + 1e-16f);

    // Phase B2: attn write
    for (int j = tid; j < deg; j += 128) {
        float4 e4; int e;
        if (j < CAP) { e4 = exp_l[j]; e = eid_l[j]; }
        else {
            const int s = csr_src[row0 + j];
            e = csr_eid[row0 + j];
            const float4 av = *(const float4*)(as_ + (size_t)s * HH);
            float4 l;
            l.x = leaky(av.x + adv.x); l.y = leaky(av.y + adv.y);
            l.z = leaky(av.z + adv.z); l.w = leaky(av.w + adv.w);
            e4.x = expf(l.x - mx.x); e4.y = expf(l.y - mx.y);
            e4.z = expf(l.z - mx.z); e4.w = expf(l.w - mx.w);
        }
        float4 a;
        a.x = e4.x * inv.x; a.y = e4.y * inv.y;
        a.z = e4.z * inv.z; a.w = e4.w * inv.w;
        *(float4*)(attn + (size_t)e * HH) = a;
    }
    __syncthreads();

    // Phase C: message aggregation; channel c = tid, head = tid>>5
    const int hsel = tid >> 5;
    const float invh = (hsel == 0) ? inv.x : (hsel == 1) ? inv.y : (hsel == 2) ? inv.z : inv.w;
    float acc = 0.f;
    const int dcap = deg < CAP ? deg : CAP;
    const float* el = (const float*)exp_l;
    #pragma unroll 4
    for (int j = 0; j < dcap; ++j) {
        const int s = __builtin_amdgcn_readfirstlane(src_l[j]);
        const float a = el[j * 4 + hsel] * invh;
        acc += H[(size_t)s * DD + tid] * a;
    }
    for (int j = dcap; j < deg; ++j) {   // spill path (deg > CAP)
        const int s = csr_src[row0 + j];
        const int e = csr_eid[row0 + j];
        const float a = attn[(size_t)e * HH + hsel];
        acc += H[(size_t)s * DD + tid] * a;
    }
    xout[(size_t)n * DD + tid] = xprev[(size_t)n * DD + tid] + acc;
}

extern "C" void kernel_launch(void* const* d_in, const int* in_sizes, int n_in,
                              void* d_out, int out_size, void* d_ws, size_t ws_size,
                              hipStream_t stream) {
    const float* x     = (const float*)d_in[0];
    const int*   ei    = (const int*)d_in[1];
    const float* W     = (const float*)d_in[2];
    const float* a_src = (const float*)d_in[3];
    const float* a_dst = (const float*)d_in[4];

    float* xs_out   = (float*)d_out;                         // [3,N,128]
    float* attn_out = xs_out + (size_t)NSTEP * NN * DD;      // [3,E,4]
    float* rel_out  = attn_out + (size_t)NSTEP * EE * HH;    // [3,E,4]

    float* h      = (float*)d_ws;                  // N*128
    float* as_    = h + (size_t)NN * DD;           // N*4
    float* ad_    = as_ + (size_t)NN * HH;         // N*4
    int*   deg    = (int*)(ad_ + (size_t)NN * HH); // N
    int*   cursor = deg + NN;                      // N
    int*   rowp   = cursor + NN;                   // N+1 (pad to 8)
    int*   csr_s  = rowp + NN + 8;                 // E
    int*   csr_e  = csr_s + EE;                    // E

    // CSR build (edge_index is constant across steps)
    zero_k<<<(NN + 255) / 256, 256, 0, stream>>>(deg, NN);
    deg_k<<<(EE + 255) / 256, 256, 0, stream>>>(ei, deg);
    scan_k<<<1, 1024, 0, stream>>>(deg, rowp, cursor);
    scat_k<<<(EE + 255) / 256, 256, 0, stream>>>(ei, rowp, cursor, csr_s, csr_e);

    const float* xprev = x;
    for (int s = 0; s < NSTEP; ++s) {
        float* xs_s = xs_out + (size_t)s * NN * DD;
        float* at_s = attn_out + (size_t)s * EE * HH;
        float* rl_s = rel_out + (size_t)s * EE * HH;

        gemm_alpha_k<<<GA_BLOCKS, 256, 0, stream>>>(xprev, W, a_src, a_dst, h, as_, ad_);
        node_k<<<NN, 128, 0, stream>>>(rowp, csr_s, csr_e, as_, ad_, h, xprev,
                                       rl_s, at_s, xs_s);
        xprev = xs_s;
    }
}

// Round 6
// 991.171 us; speedup vs baseline: 4.2065x; 1.1517x over previous
//
#include <hip/hip_runtime.h>
#include <hip/hip_bf16.h>
#include <math.h>

#define NN 50000
#define EE 1600000
#define DD 128
#define HH 4
#define NSTEP 3
#define NEG 0.2f
#define CAP 256   // LDS stash capacity per node (avg degree 32; spill path handles larger)
#define BM 32     // gemm rows per block

__device__ __forceinline__ float leaky(float v) { return v >= 0.0f ? v : NEG * v; }

__device__ __forceinline__ unsigned short bfu(float f) {
    __hip_bfloat16 b = __float2bfloat16(f);   // RNE
    return *reinterpret_cast<unsigned short*>(&b);
}
__device__ __forceinline__ float ubf(unsigned short u) {
    return __uint_as_float(((unsigned int)u) << 16);
}

// ---------------- fused h = x@W (bf16 out) and alpha dots ----------------
// 4x4 register blocking: block = 32 rows x 128 cols; thread (trow=tid>>5, tcol=tid&31)
// owns rows {4*trow..+3} x cols {4*tcol..+3}. W streamed from cache (broadcast),
// x tile staged in LDS. Alpha dots reduced over the 8 lanes of each head group.
__global__ __launch_bounds__(256) void gemm_k2(const float* __restrict__ X,
                                               const float* __restrict__ W,
                                               const float* __restrict__ a_src,
                                               const float* __restrict__ a_dst,
                                               unsigned short* __restrict__ Hb,
                                               float* __restrict__ as_,
                                               float* __restrict__ ad_) {
    __shared__ float xs[BM][132];    // pad 132 to break bank alignment
    const int tid  = threadIdx.x;
    const int tcol = tid & 31;
    const int trow = tid >> 5;
    const int row0 = blockIdx.x * BM;

    // stage x[row0..row0+31][:] (zero-fill OOB rows)
    #pragma unroll
    for (int i = 0; i < 4; ++i) {
        const int l  = tid + 256 * i;   // float4 slot 0..1023
        const int r  = l >> 5;
        const int c4 = l & 31;
        float4 v = {0.f, 0.f, 0.f, 0.f};
        if (row0 + r < NN) v = ((const float4*)(X + (size_t)(row0 + r) * DD))[c4];
        *(float4*)&xs[r][c4 * 4] = v;
    }
    __syncthreads();

    const float4* __restrict__ W4 = (const float4*)W;   // [128][32] of float4
    float4 acc0 = {0,0,0,0}, acc1 = {0,0,0,0}, acc2 = {0,0,0,0}, acc3 = {0,0,0,0};

    for (int k = 0; k < DD; k += 4) {
        float4 wv0 = W4[(k + 0) * 32 + tcol];
        float4 wv1 = W4[(k + 1) * 32 + tcol];
        float4 wv2 = W4[(k + 2) * 32 + tcol];
        float4 wv3 = W4[(k + 3) * 32 + tcol];
        float4 xv0 = *(const float4*)&xs[4 * trow + 0][k];
        float4 xv1 = *(const float4*)&xs[4 * trow + 1][k];
        float4 xv2 = *(const float4*)&xs[4 * trow + 2][k];
        float4 xv3 = *(const float4*)&xs[4 * trow + 3][k];
        #define GSTEP(ACC, XV) \
            ACC.x += XV.x * wv0.x; ACC.y += XV.x * wv0.y; ACC.z += XV.x * wv0.z; ACC.w += XV.x * wv0.w; \
            ACC.x += XV.y * wv1.x; ACC.y += XV.y * wv1.y; ACC.z += XV.y * wv1.z; ACC.w += XV.y * wv1.w; \
            ACC.x += XV.z * wv2.x; ACC.y += XV.z * wv2.y; ACC.z += XV.z * wv2.z; ACC.w += XV.z * wv2.w; \
            ACC.x += XV.w * wv3.x; ACC.y += XV.w * wv3.y; ACC.z += XV.w * wv3.z; ACC.w += XV.w * wv3.w;
        GSTEP(acc0, xv0) GSTEP(acc1, xv1) GSTEP(acc2, xv2) GSTEP(acc3, xv3)
        #undef GSTEP
    }

    // alpha partials: cols 4*tcol..+3 all lie in head (tcol>>3); a_* flat index == col
    const float4 asv = ((const float4*)a_src)[tcol];
    const float4 adv = ((const float4*)a_dst)[tcol];
    float ps0 = acc0.x*asv.x + acc0.y*asv.y + acc0.z*asv.z + acc0.w*asv.w;
    float ps1 = acc1.x*asv.x + acc1.y*asv.y + acc1.z*asv.z + acc1.w*asv.w;
    float ps2 = acc2.x*asv.x + acc2.y*asv.y + acc2.z*asv.z + acc2.w*asv.w;
    float ps3 = acc3.x*asv.x + acc3.y*asv.y + acc3.z*asv.z + acc3.w*asv.w;
    float pd0 = acc0.x*adv.x + acc0.y*adv.y + acc0.z*adv.z + acc0.w*adv.w;
    float pd1 = acc1.x*adv.x + acc1.y*adv.y + acc1.z*adv.z + acc1.w*adv.w;
    float pd2 = acc2.x*adv.x + acc2.y*adv.y + acc2.z*adv.z + acc2.w*adv.w;
    float pd3 = acc3.x*adv.x + acc3.y*adv.y + acc3.z*adv.z + acc3.w*adv.w;
    #pragma unroll
    for (int off = 1; off < 8; off <<= 1) {   // reduce 8 lanes of the head group
        ps0 += __shfl_xor(ps0, off); ps1 += __shfl_xor(ps1, off);
        ps2 += __shfl_xor(ps2, off); ps3 += __shfl_xor(ps3, off);
        pd0 += __shfl_xor(pd0, off); pd1 += __shfl_xor(pd1, off);
        pd2 += __shfl_xor(pd2, off); pd3 += __shfl_xor(pd3, off);
    }

    // H write (bf16, 8B per row per thread)
    #pragma unroll
    for (int i = 0; i < 4; ++i) {
        const int row = row0 + 4 * trow + i;
        if (row >= NN) break;
        const float4 a = (i == 0) ? acc0 : (i == 1) ? acc1 : (i == 2) ? acc2 : acc3;
        ushort4 p;
        p.x = bfu(a.x); p.y = bfu(a.y); p.z = bfu(a.z); p.w = bfu(a.w);
        *(ushort4*)&Hb[(size_t)row * DD + 4 * tcol] = p;
    }
    if ((tcol & 7) == 0) {
        const int head = tcol >> 3;
        #pragma unroll
        for (int i = 0; i < 4; ++i) {
            const int row = row0 + 4 * trow + i;
            if (row >= NN) break;
            const float ps = (i == 0) ? ps0 : (i == 1) ? ps1 : (i == 2) ? ps2 : ps3;
            const float pd = (i == 0) ? pd0 : (i == 1) ? pd1 : (i == 2) ? pd2 : pd3;
            as_[(size_t)row * HH + head] = ps;
            ad_[(size_t)row * HH + head] = pd;
        }
    }
}

// ---------------- CSR build ----------------
__global__ __launch_bounds__(256) void zero_k(int* __restrict__ p, int n) {
    const int i = blockIdx.x * 256 + threadIdx.x;
    if (i < n) p[i] = 0;
}

__global__ __launch_bounds__(256) void deg_k(const int* __restrict__ ei, int* __restrict__ deg) {
    const int e = blockIdx.x * 256 + threadIdx.x;
    if (e < EE) atomicAdd(&deg[ei[EE + e]], 1);
}

__global__ __launch_bounds__(1024) void scan_k(const int* __restrict__ deg,
                                               int* __restrict__ row_ptr,
                                               int* __restrict__ cursor) {
    __shared__ int part[1024];
    const int tid = threadIdx.x;
    const int per = (NN + 1023) / 1024;
    const int base = tid * per;
    int sum = 0;
    for (int i = 0; i < per; ++i) {
        const int idx = base + i;
        if (idx < NN) sum += deg[idx];
    }
    part[tid] = sum;
    __syncthreads();
    for (int off = 1; off < 1024; off <<= 1) {
        const int v = part[tid];
        const int add = (tid >= off) ? part[tid - off] : 0;
        __syncthreads();
        part[tid] = v + add;
        __syncthreads();
    }
    int run = (tid == 0) ? 0 : part[tid - 1];
    for (int i = 0; i < per; ++i) {
        const int idx = base + i;
        if (idx < NN) {
            row_ptr[idx] = run;
            run += deg[idx];
            cursor[idx] = 0;
        }
    }
    if (tid == 1023) row_ptr[NN] = run;
}

__global__ __launch_bounds__(256) void scat_k(const int* __restrict__ ei,
                                              const int* __restrict__ row_ptr,
                                              int* __restrict__ cursor,
                                              int* __restrict__ csr_src,
                                              int* __restrict__ csr_eid) {
    const int e = blockIdx.x * 256 + threadIdx.x;
    if (e >= EE) return;
    const int s = ei[e], d = ei[EE + e];
    const int pos = row_ptr[d] + atomicAdd(&cursor[d], 1);
    csr_src[pos] = s;
    csr_eid[pos] = e;
}

// ---------------- fused per-destination edge phase ----------------
__global__ __launch_bounds__(128) void node_k(const int* __restrict__ row_ptr,
                                              const int* __restrict__ csr_src,
                                              const int* __restrict__ csr_eid,
                                              const float* __restrict__ as_,
                                              const float* __restrict__ ad_,
                                              const unsigned short* __restrict__ Hb,
                                              const float* __restrict__ xprev,
                                              float* __restrict__ rel,
                                              float* __restrict__ attn,
                                              float* __restrict__ xout) {
    __shared__ int    src_l[CAP];
    __shared__ int    eid_l[CAP];
    __shared__ float4 exp_l[CAP];
    __shared__ float4 redbuf[2];

    const int n = blockIdx.x;
    const int tid = threadIdx.x;
    const int row0 = row_ptr[n];
    const int deg = row_ptr[n + 1] - row0;

    if (deg == 0) {
        xout[(size_t)n * DD + tid] = xprev[(size_t)n * DD + tid];
        return;
    }

    const float4 adv = *(const float4*)(ad_ + (size_t)n * HH);

    // Phase A: logits -> rel, stash, per-thread max
    float4 mx = {-INFINITY, -INFINITY, -INFINITY, -INFINITY};
    for (int j = tid; j < deg; j += 128) {
        const int s = csr_src[row0 + j];
        const int e = csr_eid[row0 + j];
        const float4 av = *(const float4*)(as_ + (size_t)s * HH);
        float4 l;
        l.x = leaky(av.x + adv.x); l.y = leaky(av.y + adv.y);
        l.z = leaky(av.z + adv.z); l.w = leaky(av.w + adv.w);
        *(float4*)(rel + (size_t)e * HH) = l;
        if (j < CAP) { src_l[j] = s; eid_l[j] = e; exp_l[j] = l; }
        mx.x = fmaxf(mx.x, l.x); mx.y = fmaxf(mx.y, l.y);
        mx.z = fmaxf(mx.z, l.z); mx.w = fmaxf(mx.w, l.w);
    }
    #pragma unroll
    for (int off = 1; off < 64; off <<= 1) {
        mx.x = fmaxf(mx.x, __shfl_xor(mx.x, off));
        mx.y = fmaxf(mx.y, __shfl_xor(mx.y, off));
        mx.z = fmaxf(mx.z, __shfl_xor(mx.z, off));
        mx.w = fmaxf(mx.w, __shfl_xor(mx.w, off));
    }
    if ((tid & 63) == 0) redbuf[tid >> 6] = mx;
    __syncthreads();
    {
        const float4 a = redbuf[0], b = redbuf[1];
        mx.x = fmaxf(a.x, b.x); mx.y = fmaxf(a.y, b.y);
        mx.z = fmaxf(a.z, b.z); mx.w = fmaxf(a.w, b.w);
    }
    __syncthreads();

    // Phase B: exp, denom
    float4 ds = {0.f, 0.f, 0.f, 0.f};
    for (int j = tid; j < deg; j += 128) {
        float4 l;
        if (j < CAP) l = exp_l[j];
        else {
            const int s = csr_src[row0 + j];
            const float4 av = *(const float4*)(as_ + (size_t)s * HH);
            l.x = leaky(av.x + adv.x); l.y = leaky(av.y + adv.y);
            l.z = leaky(av.z + adv.z); l.w = leaky(av.w + adv.w);
        }
        float4 e4;
        e4.x = expf(l.x - mx.x); e4.y = expf(l.y - mx.y);
        e4.z = expf(l.z - mx.z); e4.w = expf(l.w - mx.w);
        if (j < CAP) exp_l[j] = e4;
        ds.x += e4.x; ds.y += e4.y; ds.z += e4.z; ds.w += e4.w;
    }
    #pragma unroll
    for (int off = 1; off < 64; off <<= 1) {
        ds.x += __shfl_xor(ds.x, off); ds.y += __shfl_xor(ds.y, off);
        ds.z += __shfl_xor(ds.z, off); ds.w += __shfl_xor(ds.w, off);
    }
    if ((tid & 63) == 0) redbuf[tid >> 6] = ds;
    __syncthreads();
    {
        const float4 a = redbuf[0], b = redbuf[1];
        ds.x = a.x + b.x; ds.y = a.y + b.y; ds.z = a.z + b.z; ds.w = a.w + b.w;
    }
    float4 inv;
    inv.x = 1.0f / (ds.x + 1e-16f); inv.y = 1.0f / (ds.y + 1e-16f);
    inv.z = 1.0f / (ds.z + 1e-16f); inv.w = 1.0f / (ds.w + 1e-16f);

    // Phase B2: attn write
    for (int j = tid; j < deg; j += 128) {
        float4 e4; int e;
        if (j < CAP) { e4 = exp_l[j]; e = eid_l[j]; }
        else {
            const int s = csr_src[row0 + j];
            e = csr_eid[row0 + j];
            const float4 av = *(const float4*)(as_ + (size_t)s * HH);
            float4 l;
            l.x = leaky(av.x + adv.x); l.y = leaky(av.y + adv.y);
            l.z = leaky(av.z + adv.z); l.w = leaky(av.w + adv.w);
            e4.x = expf(l.x - mx.x); e4.y = expf(l.y - mx.y);
            e4.z = expf(l.z - mx.z); e4.w = expf(l.w - mx.w);
        }
        float4 a;
        a.x = e4.x * inv.x; a.y = e4.y * inv.y;
        a.z = e4.z * inv.z; a.w = e4.w * inv.w;
        *(float4*)(attn + (size_t)e * HH) = a;
    }
    __syncthreads();

    // Phase C: message aggregation; channel c = tid, head = tid>>5 (H in bf16)
    const int hsel = tid >> 5;
    const float invh = (hsel == 0) ? inv.x : (hsel == 1) ? inv.y : (hsel == 2) ? inv.z : inv.w;
    float acc = 0.f;
    const int dcap = deg < CAP ? deg : CAP;
    const float* el = (const float*)exp_l;
    #pragma unroll 4
    for (int j = 0; j < dcap; ++j) {
        const int s = __builtin_amdgcn_readfirstlane(src_l[j]);
        const float a = el[j * 4 + hsel] * invh;
        acc += ubf(Hb[(size_t)s * DD + tid]) * a;
    }
    for (int j = dcap; j < deg; ++j) {   // spill path (deg > CAP)
        const int s = csr_src[row0 + j];
        const int e = csr_eid[row0 + j];
        const float a = attn[(size_t)e * HH + hsel];
        acc += ubf(Hb[(size_t)s * DD + tid]) * a;
    }
    xout[(size_t)n * DD + tid] = xprev[(size_t)n * DD + tid] + acc;
}

extern "C" void kernel_launch(void* const* d_in, const int* in_sizes, int n_in,
                              void* d_out, int out_size, void* d_ws, size_t ws_size,
                              hipStream_t stream) {
    const float* x     = (const float*)d_in[0];
    const int*   ei    = (const int*)d_in[1];
    const float* W     = (const float*)d_in[2];
    const float* a_src = (const float*)d_in[3];
    const float* a_dst = (const float*)d_in[4];

    float* xs_out   = (float*)d_out;                         // [3,N,128]
    float* attn_out = xs_out + (size_t)NSTEP * NN * DD;      // [3,E,4]
    float* rel_out  = attn_out + (size_t)NSTEP * EE * HH;    // [3,E,4]

    unsigned short* hb = (unsigned short*)d_ws;              // N*128 bf16
    float* as_    = (float*)(hb + (size_t)NN * DD);          // N*4
    float* ad_    = as_ + (size_t)NN * HH;                   // N*4
    int*   deg    = (int*)(ad_ + (size_t)NN * HH);           // N
    int*   cursor = deg + NN;                                // N
    int*   rowp   = cursor + NN;                             // N+1 (pad to 8)
    int*   csr_s  = rowp + NN + 8;                           // E
    int*   csr_e  = csr_s + EE;                              // E

    // CSR build (edge_index is constant across steps)
    zero_k<<<(NN + 255) / 256, 256, 0, stream>>>(deg, NN);
    deg_k<<<(EE + 255) / 256, 256, 0, stream>>>(ei, deg);
    scan_k<<<1, 1024, 0, stream>>>(deg, rowp, cursor);
    scat_k<<<(EE + 255) / 256, 256, 0, stream>>>(ei, rowp, cursor, csr_s, csr_e);

    const float* xprev = x;
    for (int s = 0; s < NSTEP; ++s) {
        float* xs_s = xs_out + (size_t)s * NN * DD;
        float* at_s = attn_out + (size_t)s * EE * HH;
        float* rl_s = rel_out + (size_t)s * EE * HH;

        gemm_k2<<<(NN + BM - 1) / BM, 256, 0, stream>>>(xprev, W, a_src, a_dst, hb, as_, ad_);
        node_k<<<NN, 128, 0, stream>>>(rowp, csr_s, csr_e, as_, ad_, hb, xprev,
                                       rl_s, at_s, xs_s);
        xprev = xs_s;
    }
}

// Round 7
// 700.938 us; speedup vs baseline: 5.9483x; 1.4141x over previous
//
#include <hip/hip_runtime.h>
#include <hip/hip_bf16.h>
#include <math.h>

#define NN 50000
#define EE 1600000
#define DD 128
#define HH 4
#define NSTEP 3
#define NEG 0.2f
#define BM 32     // gemm rows per block
#define NPB 8     // nodes per block in node_k2
#define CAPN 96   // per-node LDS stash (deg ~ Poisson(32); spill path correct anyway)

__device__ __forceinline__ float leaky(float v) { return v >= 0.0f ? v : NEG * v; }

__device__ __forceinline__ unsigned short bfu(float f) {
    __hip_bfloat16 b = __float2bfloat16(f);   // RNE
    return *reinterpret_cast<unsigned short*>(&b);
}
__device__ __forceinline__ float ubf(unsigned short u) {
    return __uint_as_float(((unsigned int)u) << 16);
}

// ---------------- fused h = x@W (bf16 out) and alpha dots ----------------
__global__ __launch_bounds__(256) void gemm_k2(const float* __restrict__ X,
                                               const float* __restrict__ W,
                                               const float* __restrict__ a_src,
                                               const float* __restrict__ a_dst,
                                               unsigned short* __restrict__ Hb,
                                               float* __restrict__ as_,
                                               float* __restrict__ ad_) {
    __shared__ float xs[BM][132];
    const int tid  = threadIdx.x;
    const int tcol = tid & 31;
    const int trow = tid >> 5;
    const int row0 = blockIdx.x * BM;

    #pragma unroll
    for (int i = 0; i < 4; ++i) {
        const int l  = tid + 256 * i;
        const int r  = l >> 5;
        const int c4 = l & 31;
        float4 v = {0.f, 0.f, 0.f, 0.f};
        if (row0 + r < NN) v = ((const float4*)(X + (size_t)(row0 + r) * DD))[c4];
        *(float4*)&xs[r][c4 * 4] = v;
    }
    __syncthreads();

    const float4* __restrict__ W4 = (const float4*)W;
    float4 acc0 = {0,0,0,0}, acc1 = {0,0,0,0}, acc2 = {0,0,0,0}, acc3 = {0,0,0,0};

    for (int k = 0; k < DD; k += 4) {
        float4 wv0 = W4[(k + 0) * 32 + tcol];
        float4 wv1 = W4[(k + 1) * 32 + tcol];
        float4 wv2 = W4[(k + 2) * 32 + tcol];
        float4 wv3 = W4[(k + 3) * 32 + tcol];
        float4 xv0 = *(const float4*)&xs[4 * trow + 0][k];
        float4 xv1 = *(const float4*)&xs[4 * trow + 1][k];
        float4 xv2 = *(const float4*)&xs[4 * trow + 2][k];
        float4 xv3 = *(const float4*)&xs[4 * trow + 3][k];
        #define GSTEP(ACC, XV) \
            ACC.x += XV.x * wv0.x; ACC.y += XV.x * wv0.y; ACC.z += XV.x * wv0.z; ACC.w += XV.x * wv0.w; \
            ACC.x += XV.y * wv1.x; ACC.y += XV.y * wv1.y; ACC.z += XV.y * wv1.z; ACC.w += XV.y * wv1.w; \
            ACC.x += XV.z * wv2.x; ACC.y += XV.z * wv2.y; ACC.z += XV.z * wv2.z; ACC.w += XV.z * wv2.w; \
            ACC.x += XV.w * wv3.x; ACC.y += XV.w * wv3.y; ACC.z += XV.w * wv3.z; ACC.w += XV.w * wv3.w;
        GSTEP(acc0, xv0) GSTEP(acc1, xv1) GSTEP(acc2, xv2) GSTEP(acc3, xv3)
        #undef GSTEP
    }

    const float4 asv = ((const float4*)a_src)[tcol];
    const float4 adv = ((const float4*)a_dst)[tcol];
    float ps0 = acc0.x*asv.x + acc0.y*asv.y + acc0.z*asv.z + acc0.w*asv.w;
    float ps1 = acc1.x*asv.x + acc1.y*asv.y + acc1.z*asv.z + acc1.w*asv.w;
    float ps2 = acc2.x*asv.x + acc2.y*asv.y + acc2.z*asv.z + acc2.w*asv.w;
    float ps3 = acc3.x*asv.x + acc3.y*asv.y + acc3.z*asv.z + acc3.w*asv.w;
    float pd0 = acc0.x*adv.x + acc0.y*adv.y + acc0.z*adv.z + acc0.w*adv.w;
    float pd1 = acc1.x*adv.x + acc1.y*adv.y + acc1.z*adv.z + acc1.w*adv.w;
    float pd2 = acc2.x*adv.x + acc2.y*adv.y + acc2.z*adv.z + acc2.w*adv.w;
    float pd3 = acc3.x*adv.x + acc3.y*adv.y + acc3.z*adv.z + acc3.w*adv.w;
    #pragma unroll
    for (int off = 1; off < 8; off <<= 1) {
        ps0 += __shfl_xor(ps0, off); ps1 += __shfl_xor(ps1, off);
        ps2 += __shfl_xor(ps2, off); ps3 += __shfl_xor(ps3, off);
        pd0 += __shfl_xor(pd0, off); pd1 += __shfl_xor(pd1, off);
        pd2 += __shfl_xor(pd2, off); pd3 += __shfl_xor(pd3, off);
    }

    #pragma unroll
    for (int i = 0; i < 4; ++i) {
        const int row = row0 + 4 * trow + i;
        if (row >= NN) break;
        const float4 a = (i == 0) ? acc0 : (i == 1) ? acc1 : (i == 2) ? acc2 : acc3;
        ushort4 p;
        p.x = bfu(a.x); p.y = bfu(a.y); p.z = bfu(a.z); p.w = bfu(a.w);
        *(ushort4*)&Hb[(size_t)row * DD + 4 * tcol] = p;
    }
    if ((tcol & 7) == 0) {
        const int head = tcol >> 3;
        #pragma unroll
        for (int i = 0; i < 4; ++i) {
            const int row = row0 + 4 * trow + i;
            if (row >= NN) break;
            const float ps = (i == 0) ? ps0 : (i == 1) ? ps1 : (i == 2) ? ps2 : ps3;
            const float pd = (i == 0) ? pd0 : (i == 1) ? pd1 : (i == 2) ? pd2 : pd3;
            as_[(size_t)row * HH + head] = ps;
            ad_[(size_t)row * HH + head] = pd;
        }
    }
}

// ---------------- CSR build ----------------
__global__ __launch_bounds__(256) void zero_k(int* __restrict__ p, int n) {
    const int i = blockIdx.x * 256 + threadIdx.x;
    if (i < n) p[i] = 0;
}

__global__ __launch_bounds__(256) void deg_k(const int* __restrict__ ei, int* __restrict__ deg) {
    const int e = blockIdx.x * 256 + threadIdx.x;
    if (e < EE) atomicAdd(&deg[ei[EE + e]], 1);
}

__global__ __launch_bounds__(1024) void scan_k(const int* __restrict__ deg,
                                               int* __restrict__ row_ptr,
                                               int* __restrict__ cursor) {
    __shared__ int part[1024];
    const int tid = threadIdx.x;
    const int per = (NN + 1023) / 1024;
    const int base = tid * per;
    int sum = 0;
    for (int i = 0; i < per; ++i) {
        const int idx = base + i;
        if (idx < NN) sum += deg[idx];
    }
    part[tid] = sum;
    __syncthreads();
    for (int off = 1; off < 1024; off <<= 1) {
        const int v = part[tid];
        const int add = (tid >= off) ? part[tid - off] : 0;
        __syncthreads();
        part[tid] = v + add;
        __syncthreads();
    }
    int run = (tid == 0) ? 0 : part[tid - 1];
    for (int i = 0; i < per; ++i) {
        const int idx = base + i;
        if (idx < NN) {
            row_ptr[idx] = run;
            run += deg[idx];
            cursor[idx] = 0;
        }
    }
    if (tid == 1023) row_ptr[NN] = run;
}

__global__ __launch_bounds__(256) void scat_k(const int* __restrict__ ei,
                                              const int* __restrict__ row_ptr,
                                              int* __restrict__ cursor,
                                              int2* __restrict__ csr) {
    const int e = blockIdx.x * 256 + threadIdx.x;
    if (e >= EE) return;
    const int s = ei[e], d = ei[EE + e];
    const int pos = row_ptr[d] + atomicAdd(&cursor[d], 1);
    int2 se; se.x = s; se.y = e;
    csr[pos] = se;
}

// ---------------- fused per-destination edge phase (8 nodes / block) ----------------
// node group = 32 lanes; no __syncthreads (all stash traffic is same-wave).
__global__ __launch_bounds__(256) void node_k2(const int* __restrict__ row_ptr,
                                               const int2* __restrict__ csr,
                                               const float* __restrict__ as_,
                                               const float* __restrict__ ad_,
                                               const unsigned short* __restrict__ Hb,
                                               const float* __restrict__ xprev,
                                               float* __restrict__ rel,
                                               float* __restrict__ attn,
                                               float* __restrict__ xout) {
    __shared__ int    src_l[NPB][CAPN];
    __shared__ int    eid_l[NPB][CAPN];
    __shared__ float4 exp_l[NPB][CAPN];

    const int tid  = threadIdx.x;
    const int nl   = tid >> 5;    // node slot in block
    const int lane = tid & 31;
    const int n    = blockIdx.x * NPB + nl;

    const int row0 = row_ptr[n];
    const int deg  = row_ptr[n + 1] - row0;

    if (deg == 0) {
        ((float4*)(xout + (size_t)n * DD))[lane] = ((const float4*)(xprev + (size_t)n * DD))[lane];
        return;
    }

    const float4 adv = *(const float4*)(ad_ + (size_t)n * HH);

    // Phase A: logits -> rel, stash, group max
    float4 mx = {-INFINITY, -INFINITY, -INFINITY, -INFINITY};
    for (int j = lane; j < deg; j += 32) {
        const int2 se = csr[row0 + j];
        const float4 av = *(const float4*)(as_ + (size_t)se.x * HH);
        float4 l;
        l.x = leaky(av.x + adv.x); l.y = leaky(av.y + adv.y);
        l.z = leaky(av.z + adv.z); l.w = leaky(av.w + adv.w);
        *(float4*)(rel + (size_t)se.y * HH) = l;
        if (j < CAPN) { src_l[nl][j] = se.x; eid_l[nl][j] = se.y; exp_l[nl][j] = l; }
        mx.x = fmaxf(mx.x, l.x); mx.y = fmaxf(mx.y, l.y);
        mx.z = fmaxf(mx.z, l.z); mx.w = fmaxf(mx.w, l.w);
    }
    #pragma unroll
    for (int off = 1; off < 32; off <<= 1) {
        mx.x = fmaxf(mx.x, __shfl_xor(mx.x, off));
        mx.y = fmaxf(mx.y, __shfl_xor(mx.y, off));
        mx.z = fmaxf(mx.z, __shfl_xor(mx.z, off));
        mx.w = fmaxf(mx.w, __shfl_xor(mx.w, off));
    }

    // Phase B: exp + group denom
    float4 ds = {0.f, 0.f, 0.f, 0.f};
    for (int j = lane; j < deg; j += 32) {
        float4 l;
        if (j < CAPN) l = exp_l[nl][j];
        else {
            const int2 se = csr[row0 + j];
            const float4 av = *(const float4*)(as_ + (size_t)se.x * HH);
            l.x = leaky(av.x + adv.x); l.y = leaky(av.y + adv.y);
            l.z = leaky(av.z + adv.z); l.w = leaky(av.w + adv.w);
        }
        float4 e4;
        e4.x = expf(l.x - mx.x); e4.y = expf(l.y - mx.y);
        e4.z = expf(l.z - mx.z); e4.w = expf(l.w - mx.w);
        if (j < CAPN) exp_l[nl][j] = e4;
        ds.x += e4.x; ds.y += e4.y; ds.z += e4.z; ds.w += e4.w;
    }
    #pragma unroll
    for (int off = 1; off < 32; off <<= 1) {
        ds.x += __shfl_xor(ds.x, off); ds.y += __shfl_xor(ds.y, off);
        ds.z += __shfl_xor(ds.z, off); ds.w += __shfl_xor(ds.w, off);
    }
    float4 inv;
    inv.x = 1.0f / (ds.x + 1e-16f); inv.y = 1.0f / (ds.y + 1e-16f);
    inv.z = 1.0f / (ds.z + 1e-16f); inv.w = 1.0f / (ds.w + 1e-16f);

    // Phase B2: attn write
    for (int j = lane; j < deg; j += 32) {
        float4 e4; int e;
        if (j < CAPN) { e4 = exp_l[nl][j]; e = eid_l[nl][j]; }
        else {
            const int2 se = csr[row0 + j];
            e = se.y;
            const float4 av = *(const float4*)(as_ + (size_t)se.x * HH);
            float4 l;
            l.x = leaky(av.x + adv.x); l.y = leaky(av.y + adv.y);
            l.z = leaky(av.z + adv.z); l.w = leaky(av.w + adv.w);
            e4.x = expf(l.x - mx.x); e4.y = expf(l.y - mx.y);
            e4.z = expf(l.z - mx.z); e4.w = expf(l.w - mx.w);
        }
        float4 a;
        a.x = e4.x * inv.x; a.y = e4.y * inv.y;
        a.z = e4.z * inv.z; a.w = e4.w * inv.w;
        *(float4*)(attn + (size_t)e * HH) = a;
    }

    // Phase C: aggregation — lane owns channels 4*lane..+3 (head = lane>>3)
    const int hsel = lane >> 3;
    const float invh = (hsel == 0) ? inv.x : (hsel == 1) ? inv.y : (hsel == 2) ? inv.z : inv.w;
    float4 acc = {0.f, 0.f, 0.f, 0.f};
    const int dcap = deg < CAPN ? deg : CAPN;
    #pragma unroll 4
    for (int j = 0; j < dcap; ++j) {
        const int s = src_l[nl][j];
        const float a = ((const float*)&exp_l[nl][j])[hsel] * invh;
        const ushort4 hv = *(const ushort4*)&Hb[(size_t)s * DD + 4 * lane];
        acc.x += ubf(hv.x) * a; acc.y += ubf(hv.y) * a;
        acc.z += ubf(hv.z) * a; acc.w += ubf(hv.w) * a;
    }
    for (int j = dcap; j < deg; ++j) {   // spill: recompute attn from as_ (no global RAW)
        const int2 se = csr[row0 + j];
        const float4 av = *(const float4*)(as_ + (size_t)se.x * HH);
        float4 l;
        l.x = leaky(av.x + adv.x); l.y = leaky(av.y + adv.y);
        l.z = leaky(av.z + adv.z); l.w = leaky(av.w + adv.w);
        const float lh = (hsel == 0) ? l.x : (hsel == 1) ? l.y : (hsel == 2) ? l.z : l.w;
        const float mh = (hsel == 0) ? mx.x : (hsel == 1) ? mx.y : (hsel == 2) ? mx.z : mx.w;
        const float a = expf(lh - mh) * invh;
        const ushort4 hv = *(const ushort4*)&Hb[(size_t)se.x * DD + 4 * lane];
        acc.x += ubf(hv.x) * a; acc.y += ubf(hv.y) * a;
        acc.z += ubf(hv.z) * a; acc.w += ubf(hv.w) * a;
    }
    const float4 xv = ((const float4*)(xprev + (size_t)n * DD))[lane];
    float4 o;
    o.x = xv.x + acc.x; o.y = xv.y + acc.y; o.z = xv.z + acc.z; o.w = xv.w + acc.w;
    ((float4*)(xout + (size_t)n * DD))[lane] = o;
}

extern "C" void kernel_launch(void* const* d_in, const int* in_sizes, int n_in,
                              void* d_out, int out_size, void* d_ws, size_t ws_size,
                              hipStream_t stream) {
    const float* x     = (const float*)d_in[0];
    const int*   ei    = (const int*)d_in[1];
    const float* W     = (const float*)d_in[2];
    const float* a_src = (const float*)d_in[3];
    const float* a_dst = (const float*)d_in[4];

    float* xs_out   = (float*)d_out;                         // [3,N,128]
    float* attn_out = xs_out + (size_t)NSTEP * NN * DD;      // [3,E,4]
    float* rel_out  = attn_out + (size_t)NSTEP * EE * HH;    // [3,E,4]

    unsigned short* hb = (unsigned short*)d_ws;              // N*128 bf16
    float* as_    = (float*)(hb + (size_t)NN * DD);          // N*4
    float* ad_    = as_ + (size_t)NN * HH;                   // N*4
    int*   deg    = (int*)(ad_ + (size_t)NN * HH);           // N
    int*   cursor = deg + NN;                                // N
    int*   rowp   = cursor + NN;                             // N+1 (pad to 8)
    int2*  csr    = (int2*)(rowp + NN + 8);                  // E (src,eid)

    // CSR build (edge_index is constant across steps)
    zero_k<<<(NN + 255) / 256, 256, 0, stream>>>(deg, NN);
    deg_k<<<(EE + 255) / 256, 256, 0, stream>>>(ei, deg);
    scan_k<<<1, 1024, 0, stream>>>(deg, rowp, cursor);
    scat_k<<<(EE + 255) / 256, 256, 0, stream>>>(ei, rowp, cursor, csr);

    const float* xprev = x;
    for (int s = 0; s < NSTEP; ++s) {
        float* xs_s = xs_out + (size_t)s * NN * DD;
        float* at_s = attn_out + (size_t)s * EE * HH;
        float* rl_s = rel_out + (size_t)s * EE * HH;

        gemm_k2<<<(NN + BM - 1) / BM, 256, 0, stream>>>(xprev, W, a_src, a_dst, hb, as_, ad_);
        node_k2<<<NN / NPB, 256, 0, stream>>>(rowp, csr, as_, ad_, hb, xprev,
                                              rl_s, at_s, xs_s);
        xprev = xs_s;
    }
}